// Round 6
// baseline (193.886 us; speedup 1.0000x reference)
//
#include <hip/hip_runtime.h>
#include <stdint.h>

#define NROWS 256
#define NCOLS 65536
#define KCL   64
#define TMAX  20        // max 1280 elements per cluster (mean 1024, sd 32 -> 8 sigma)
#define NBLK  128       // counting-sort blocks
#define CHUNK (NCOLS / NBLK)   // 512 elements per block

// ---- Threefry-2x32 (exact JAX semantics, partitionable scheme) -------------
__device__ __forceinline__ void tf2x32(uint32_t k0, uint32_t k1,
                                       uint32_t x0, uint32_t x1,
                                       uint32_t& o0, uint32_t& o1) {
  const uint32_t ks2 = k0 ^ k1 ^ 0x1BD11BDAu;
  x0 += k0; x1 += k1;
#define TFR(r) { x0 += x1; x1 = (x1 << (r)) | (x1 >> (32 - (r))); x1 ^= x0; }
  TFR(13) TFR(15) TFR(26) TFR(6)
  x0 += k1; x1 += ks2 + 1u;
  TFR(17) TFR(29) TFR(16) TFR(24)
  x0 += ks2; x1 += k0 + 2u;
  TFR(13) TFR(15) TFR(26) TFR(6)
  x0 += k0; x1 += k1 + 3u;
  TFR(17) TFR(29) TFR(16) TFR(24)
  x0 += k1; x1 += ks2 + 4u;
  TFR(13) TFR(15) TFR(26) TFR(6)
  x0 += ks2; x1 += k0 + 5u;
#undef TFR
  o0 = x0; o1 = x1;
}

__device__ __forceinline__ uint32_t jax_bits(uint32_t k0, uint32_t k1, uint32_t f) {
  uint32_t o0, o1;
  tf2x32(k0, k1, 0u, f, o0, o1);
  return o0 ^ o1;
}

__device__ __forceinline__ float bits_to_u01(uint32_t bits) {
  return __uint_as_float((bits >> 9) | 0x3f800000u) - 1.0f;
}

__device__ __forceinline__ float key_from_ubits(uint32_t ubits, float kf) {
  // key = k + u*0.999f : separate mul/add, round-to-nearest, NO fma
  return __fadd_rn(kf, __fmul_rn(bits_to_u01(ubits), 0.999f));
}

// ---- wave-level reductions (64 lanes, no LDS, no barriers) -----------------
__device__ __forceinline__ int wave_sum_i(int v) {
#pragma unroll
  for (int m = 1; m < 64; m <<= 1) v += __shfl_xor(v, m, 64);
  return v;
}
__device__ __forceinline__ uint32_t wave_min_u(uint32_t v) {
#pragma unroll
  for (int m = 1; m < 64; m <<= 1) {
    const uint32_t o = (uint32_t)__shfl_xor((int)v, m, 64);
    v = (o < v) ? o : v;
  }
  return v;
}
__device__ __forceinline__ int wave_min_i(int v) {
#pragma unroll
  for (int m = 1; m < 64; m <<= 1) {
    const int o = __shfl_xor(v, m, 64);
    v = (o < v) ? o : v;
  }
  return v;
}

// ---- phase 1: per-block histograms (LDS atomics only) ----------------------
__global__ __launch_bounds__(256)
void k_hist(const int* __restrict__ a, int* __restrict__ blockhist) {
  __shared__ int h[KCL];
  const int tid = threadIdx.x;
  if (tid < KCL) h[tid] = 0;
  __syncthreads();
  const int base = blockIdx.x * CHUNK;
#pragma unroll
  for (int i = base + tid; i < base + CHUNK; i += 256)
    atomicAdd(&h[a[i]], 1);
  __syncthreads();
  if (tid < KCL) blockhist[blockIdx.x * KCL + tid] = h[tid];
}

// ---- phase 2: column scan over blocks + starts + softmax/thresh + PRNG -----
__global__ void k_prefix_setup(int* __restrict__ blockhist, int* __restrict__ sizes,
                               int* __restrict__ starts,
                               const float* __restrict__ w, uint32_t* __restrict__ hdr,
                               uint32_t* __restrict__ vthresh) {
  const int k = threadIdx.x;   // 64 threads, one wave
  int acc = 0;
#pragma unroll 8
  for (int blk = 0; blk < NBLK; ++blk) {
    const int t = blockhist[blk * KCL + k];
    blockhist[blk * KCL + k] = acc;   // exclusive within cluster k
    acc += t;
  }
  sizes[k] = acc;
  // exclusive prefix over clusters via wave scan
  int scan = acc;
#pragma unroll
  for (int d = 1; d < 64; d <<= 1) {
    const int o = __shfl_up(scan, d, 64);
    if (k >= d) scan += o;
  }
  starts[k] = scan - acc;
  // softmax(w)*0.1 -> integer mantissa threshold: v<p  <=>  (vbits>>9) < vthresh
  // (u = m*2^-23 exactly; p*2^23 exact power-of-2 scale; ceil handles both cases)
  const float wk = w[k];
  float m = wk;
#pragma unroll
  for (int d = 1; d < 64; d <<= 1) m = fmaxf(m, __shfl_xor(m, d, 64));
  const float e = expf(wk - m);
  float s = e;
#pragma unroll
  for (int d = 1; d < 64; d <<= 1) s += __shfl_xor(s, d, 64);
  const float pk = (e / s) * 0.1f;
  vthresh[k] = (uint32_t)ceilf(pk * 8388608.0f);
  if (k == 0) {
    uint32_t o0, o1;
    tf2x32(0u, 42u, 0u, 0u, o0, o1); hdr[0] = o0; hdr[1] = o1;  // ku = split(key)[0]
    tf2x32(0u, 42u, 0u, 1u, o0, o1); hdr[2] = o0; hdr[3] = o1;  // kv = split(key)[1]
  }
}

// ---- phase 3: scatter with LDS cursors (zero global atomics) ---------------
__global__ __launch_bounds__(256)
void k_scatter(const int* __restrict__ a, const int* __restrict__ blockhist,
               const int* __restrict__ starts, int* __restrict__ idx_sorted) {
  __shared__ int cur[KCL];
  const int tid = threadIdx.x;
  if (tid < KCL) cur[tid] = starts[tid] + blockhist[blockIdx.x * KCL + tid];
  __syncthreads();
  const int base = blockIdx.x * CHUNK;
#pragma unroll
  for (int i = base + tid; i < base + CHUNK; i += 256) {
    const int k = a[i];
    const int slot = atomicAdd(&cur[k], 1);
    idx_sorted[slot] = i;
  }
}

// ---- main: one WAVE per (batch row, cluster); writes EVERY element ---------
// Clusters partition the columns, so the (b,k) waves collectively cover every
// (b,n) exactly once: write sel ? x : 0 -> no pre-zero pass needed. The extra
// scattered stores (~64MB) hide under the ~90us VALU hash wall (<15% HBM BW).
__global__ __launch_bounds__(256)
void k_select(const float* __restrict__ x,
              const int* __restrict__ idx_sorted,
              const int* __restrict__ sizes,
              const int* __restrict__ starts,
              const uint32_t* __restrict__ hdr,
              const uint32_t* __restrict__ vthresh,
              float* __restrict__ out) {
  const int lane = threadIdx.x & 63;
  const int pair = (blockIdx.x << 2) + (threadIdx.x >> 6);
  const int b = pair & (NROWS - 1);   // consecutive pairs share k -> idx range L2 reuse
  const int k = pair >> 8;

  int sz = sizes[k];
  const int st = starts[k];
  if (sz <= 0) return;                 // wave-uniform; empty cluster covers nothing
  if (sz > TMAX * 64) sz = TMAX * 64;  // safety clamp (cannot trigger at 8 sigma)

  const uint32_t ku0 = hdr[0], ku1 = hdr[1], kv0 = hdr[2], kv1 = hdr[3];
  const uint32_t vt = vthresh[k];
  const float kf = (float)k;
  const uint32_t bbase = (uint32_t)(b << 16);

  // --- hoist ALL idx loads first: one vmcnt wait, hash loop is pure ALU -----
  int nv[TMAX];
#pragma unroll
  for (int t = 0; t < TMAX; ++t) {
    const int j = lane + (t << 6);
    nv[t] = (j < sz) ? idx_sorted[st + j] : 0;
  }

  // --- hash u,v per element; key bits + running per-lane min in registers ---
  uint32_t kb[TMAX];
  uint32_t curmin = 0xFFFFFFFFu;
  int cnt = 0;
#pragma unroll
  for (int t = 0; t < TMAX; ++t) {
    const int j = lane + (t << 6);
    uint32_t kbv = 0xFFFFFFFFu;        // sentinel > any valid key's bits
    if (j < sz) {
      const uint32_t f = bbase + (uint32_t)nv[t];   // flat index b*65536+n
      const uint32_t ubv = jax_bits(ku0, ku1, f);
      const uint32_t vbv = jax_bits(kv0, kv1, f);
      cnt += ((vbv >> 9) < vt) ? 1 : 0;             // integer-domain bernoulli
      kbv = __float_as_uint(key_from_ubits(ubv, kf));  // key>=0 -> bits monotone
    }
    kb[t] = kbv;
    curmin = (kbv < curmin) ? kbv : curmin;
  }
  int C = wave_sum_i(cnt);
  if (C < 1) C = 1;                    // jnp.maximum(counts, 1); C <= sz

  // --- C-th smallest keybits by iterative wave-min extraction (E[C]=1.6) ----
  // curmin = per-lane min over non-consumed; only consuming lane rescans.
  uint32_t consumed = 0;
  uint32_t Tkey;
  for (int e = 0;; ++e) {
    const uint32_t wmn = wave_min_u(curmin);
    if (e == C - 1) { Tkey = wmn; break; }
    const unsigned long long bal = __ballot(curmin == wmn);
    const int src = (int)__ffsll((long long)bal) - 1;
    if (lane == src) {                 // consume exactly one instance of wmn
      int ct = -1;
#pragma unroll
      for (int t = 0; t < TMAX; ++t)
        if (ct < 0 && !((consumed >> t) & 1u) && kb[t] == wmn) ct = t;
      consumed |= (1u << ct);
      uint32_t nm = 0xFFFFFFFFu;
#pragma unroll
      for (int t = 0; t < TMAX; ++t) {
        const uint32_t v = ((consumed >> t) & 1u) ? 0xFFFFFFFFu : kb[t];
        nm = (v < nm) ? v : nm;
      }
      curmin = nm;
    }
  }

  // --- exact tie resolution on (key, original index): ONE packed reduction --
  int packed = 0;
#pragma unroll
  for (int t = 0; t < TMAX; ++t) {
    packed += (kb[t] < Tkey) ? (1 << 16) : 0;
    packed += (kb[t] == Tkey) ? 1 : 0;
  }
  const int sred = wave_sum_i(packed);
  const int nbelow = sred >> 16;
  const int tieCnt = sred & 0xFFFF;
  const int r = C - nbelow;            // 1 <= r <= tieCnt

  int cutN = 0x7FFFFFFF;               // r == tieCnt: select all tied
  if (r < tieCnt) {                    // rare: pick r smallest original indices
    uint32_t cons2 = 0;
    for (int e = 0; e < r; ++e) {
      int mnN = 0x7FFFFFFF, mnT = 0;
#pragma unroll
      for (int t = 0; t < TMAX; ++t) {
        if (kb[t] == Tkey && !((cons2 >> t) & 1u)) {
          if (nv[t] < mnN) { mnN = nv[t]; mnT = t; }
        }
      }
      const int w = wave_min_i(mnN);
      cutN = w;
      const unsigned long long bal = __ballot(mnN == w);
      const int src = (int)__ffsll((long long)bal) - 1;
      if (lane == src) cons2 |= (1u << mnT);
    }
  }

  // --- write ALL elements of this (b, cluster): sel ? x : 0 -----------------
  const size_t rowoff = (size_t)b * NCOLS;
  const bool allTies = (r >= tieCnt);
#pragma unroll
  for (int t = 0; t < TMAX; ++t) {
    const int j = lane + (t << 6);
    if (j < sz) {
      const uint32_t v = kb[t];
      bool sel = (v < Tkey);
      if (!sel && v == Tkey) sel = allTies ? true : (nv[t] <= cutN);
      const size_t off = rowoff + (uint32_t)nv[t];
      float val = 0.0f;
      if (sel) val = x[off];           // divergent load, rare (~8% of lanes)
      out[off] = val;
    }
  }
}

// ---- host-side launch ------------------------------------------------------
extern "C" void kernel_launch(void* const* d_in, const int* in_sizes, int n_in,
                              void* d_out, int out_size, void* d_ws, size_t ws_size,
                              hipStream_t stream) {
  const float* x = (const float*)d_in[0];
  const float* w = (const float*)d_in[1];
  const int* assign = (const int*)d_in[2];
  float* out = (float*)d_out;
  uint32_t* ws = (uint32_t*)d_ws;

  // workspace layout (uint32 units)
  uint32_t* hdr       = ws;                 // [4]    ku0,ku1,kv0,kv1
  uint32_t* vthresh   = ws + 4;             // [64]
  int*      sizes     = (int*)(ws + 68);    // [64]
  int*      starts    = (int*)(ws + 132);   // [64]
  int*      blockhist = (int*)(ws + 196);   // [128*64]
  int*      idxs      = (int*)(ws + 196 + NBLK * KCL);  // [65536]

  // NO output pre-zero: k_select writes every (b,n) exactly once.
  k_hist<<<NBLK, 256, 0, stream>>>(assign, blockhist);
  k_prefix_setup<<<1, 64, 0, stream>>>(blockhist, sizes, starts, w, hdr, vthresh);
  k_scatter<<<NBLK, 256, 0, stream>>>(assign, blockhist, starts, idxs);
  k_select<<<(NROWS * KCL) / 4, 256, 0, stream>>>(x, idxs, sizes, starts, hdr, vthresh, out);
  (void)n_in; (void)in_sizes; (void)ws_size;
}

// Round 7
// 98.523 us; speedup vs baseline: 1.9679x; 1.9679x over previous
//
#include <hip/hip_runtime.h>
#include <stdint.h>

#define NROWS 256
#define NCOLS 65536
#define KCL   64
#define TMAX  20        // max 1280 elements per cluster (mean 1024, sd 32 -> 8 sigma)
#define NBLK  128       // counting-sort blocks
#define CHUNK (NCOLS / NBLK)   // 512 elements per block
#define ZBLK  2048      // zero+hist blocks

// ---- Threefry-2x32 (exact JAX semantics, partitionable scheme) -------------
__device__ __forceinline__ void tf2x32(uint32_t k0, uint32_t k1,
                                       uint32_t x0, uint32_t x1,
                                       uint32_t& o0, uint32_t& o1) {
  const uint32_t ks2 = k0 ^ k1 ^ 0x1BD11BDAu;
  x0 += k0; x1 += k1;
#define TFR(r) { x0 += x1; x1 = (x1 << (r)) | (x1 >> (32 - (r))); x1 ^= x0; }
  TFR(13) TFR(15) TFR(26) TFR(6)
  x0 += k1; x1 += ks2 + 1u;
  TFR(17) TFR(29) TFR(16) TFR(24)
  x0 += ks2; x1 += k0 + 2u;
  TFR(13) TFR(15) TFR(26) TFR(6)
  x0 += k0; x1 += k1 + 3u;
  TFR(17) TFR(29) TFR(16) TFR(24)
  x0 += k1; x1 += ks2 + 4u;
  TFR(13) TFR(15) TFR(26) TFR(6)
  x0 += ks2; x1 += k0 + 5u;
#undef TFR
  o0 = x0; o1 = x1;
}

// compile-time threefry for the PRNG header: ku = split(key42)[0], kv = [1]
struct TFO { uint32_t a, b; };
constexpr TFO tf_const(uint32_t k0, uint32_t k1, uint32_t x0, uint32_t x1) {
  const uint32_t ks2 = k0 ^ k1 ^ 0x1BD11BDAu;
  x0 += k0; x1 += k1;
#define TFC(r) { x0 += x1; x1 = (x1 << (r)) | (x1 >> (32 - (r))); x1 ^= x0; }
  TFC(13) TFC(15) TFC(26) TFC(6)
  x0 += k1; x1 += ks2 + 1u;
  TFC(17) TFC(29) TFC(16) TFC(24)
  x0 += ks2; x1 += k0 + 2u;
  TFC(13) TFC(15) TFC(26) TFC(6)
  x0 += k0; x1 += k1 + 3u;
  TFC(17) TFC(29) TFC(16) TFC(24)
  x0 += k1; x1 += ks2 + 4u;
  TFC(13) TFC(15) TFC(26) TFC(6)
  x0 += ks2; x1 += k0 + 5u;
#undef TFC
  return {x0, x1};
}
constexpr TFO KU = tf_const(0u, 42u, 0u, 0u);   // jax.random.split(key(42))[0]
constexpr TFO KV = tf_const(0u, 42u, 0u, 1u);   // jax.random.split(key(42))[1]

__device__ __forceinline__ uint32_t jax_bits(uint32_t k0, uint32_t k1, uint32_t f) {
  uint32_t o0, o1;
  tf2x32(k0, k1, 0u, f, o0, o1);
  return o0 ^ o1;
}

__device__ __forceinline__ float bits_to_u01(uint32_t bits) {
  return __uint_as_float((bits >> 9) | 0x3f800000u) - 1.0f;
}

__device__ __forceinline__ float key_from_ubits(uint32_t ubits, float kf) {
  // key = k + u*0.999f : separate mul/add, round-to-nearest, NO fma
  return __fadd_rn(kf, __fmul_rn(bits_to_u01(ubits), 0.999f));
}

// ---- wave-level reductions (64 lanes, no LDS, no barriers) -----------------
__device__ __forceinline__ int wave_sum_i(int v) {
#pragma unroll
  for (int m = 1; m < 64; m <<= 1) v += __shfl_xor(v, m, 64);
  return v;
}
__device__ __forceinline__ uint32_t wave_min_u(uint32_t v) {
#pragma unroll
  for (int m = 1; m < 64; m <<= 1) {
    const uint32_t o = (uint32_t)__shfl_xor((int)v, m, 64);
    v = (o < v) ? o : v;
  }
  return v;
}
__device__ __forceinline__ int wave_min_i(int v) {
#pragma unroll
  for (int m = 1; m < 64; m <<= 1) {
    const int o = __shfl_xor(v, m, 64);
    v = (o < v) ? o : v;
  }
  return v;
}

// ---- phase 1: zero output (64 MB, mostly L3-resident) + per-block hist -----
__global__ __launch_bounds__(256)
void k_zerohist(float4* __restrict__ outv, const int* __restrict__ a,
                int* __restrict__ blockhist) {
  const int gtid = blockIdx.x * 256 + threadIdx.x;   // 524288 threads
  const float4 z = make_float4(0.f, 0.f, 0.f, 0.f);
#pragma unroll
  for (int i = 0; i < 8; ++i)                        // 4194304 float4 = 64 MB
    outv[gtid + i * (ZBLK * 256)] = z;
  if (blockIdx.x < NBLK) {
    __shared__ int h[KCL];
    if (threadIdx.x < KCL) h[threadIdx.x] = 0;
    __syncthreads();
    const int base = blockIdx.x * CHUNK;
#pragma unroll
    for (int i = base + threadIdx.x; i < base + CHUNK; i += 256)
      atomicAdd(&h[a[i]], 1);
    __syncthreads();
    if (threadIdx.x < KCL) blockhist[blockIdx.x * KCL + threadIdx.x] = h[threadIdx.x];
  }
}

// ---- phase 2 (fused prefix + scatter): each block recomputes the global ----
// prefix from blockhist (32KB, L2-broadcast-hot) -> no separate prefix kernel.
// Block 0 additionally publishes sizes/starts/vthresh for k_select.
__global__ __launch_bounds__(256)
void k_prescatter(const int* __restrict__ a, const int* __restrict__ blockhist,
                  int* __restrict__ sizes_g, int* __restrict__ starts_g,
                  const float* __restrict__ w, uint32_t* __restrict__ vthresh,
                  int* __restrict__ idx_sorted) {
  __shared__ int cur[KCL];
  const int tid = threadIdx.x;
  const int lane = tid & 63;
  const int wid = tid >> 6;
  const int blk = blockIdx.x;

  if (wid == 0) {                      // one wave: lane = cluster k
    int own = 0, tot = 0;
#pragma unroll 8
    for (int b2 = 0; b2 < NBLK; ++b2) {
      const int h = blockhist[b2 * KCL + lane];
      own += (b2 < blk) ? h : 0;       // exclusive within cluster, blocks < blk
      tot += h;                        // cluster size
    }
    int scan = tot;                    // exclusive scan over clusters -> starts
#pragma unroll
    for (int d = 1; d < 64; d <<= 1) {
      const int o = __shfl_up(scan, d, 64);
      if (lane >= d) scan += o;
    }
    const int start = scan - tot;
    cur[lane] = start + own;
    if (blk == 0) {
      sizes_g[lane] = tot;
      starts_g[lane] = start;
      // softmax(w)*0.1 -> integer mantissa threshold: v<p <=> (vbits>>9)<vthresh
      const float wk = w[lane];
      float m = wk;
#pragma unroll
      for (int d = 1; d < 64; d <<= 1) m = fmaxf(m, __shfl_xor(m, d, 64));
      const float e = expf(wk - m);
      float s = e;
#pragma unroll
      for (int d = 1; d < 64; d <<= 1) s += __shfl_xor(s, d, 64);
      vthresh[lane] = (uint32_t)ceilf((e / s) * 0.1f * 8388608.0f);
    }
  }
  __syncthreads();
  const int base = blk * CHUNK;
#pragma unroll
  for (int i = base + tid; i < base + CHUNK; i += 256) {
    const int k = a[i];
    const int slot = atomicAdd(&cur[k], 1);
    idx_sorted[slot] = i;
  }
}

// ---- main: one WAVE per (batch row, cluster); round-1 body (fastest) -------
__global__ __launch_bounds__(256)
void k_select(const float* __restrict__ x,
              const int* __restrict__ idx_sorted,
              const int* __restrict__ sizes,
              const int* __restrict__ starts,
              const uint32_t* __restrict__ vthresh,
              float* __restrict__ out) {
  const int lane = threadIdx.x & 63;
  const int pair = (blockIdx.x << 2) + (threadIdx.x >> 6);
  const int b = pair & (NROWS - 1);   // consecutive pairs share k -> idx range L2 reuse
  const int k = pair >> 8;

  int sz = sizes[k];
  const int st = starts[k];
  if (sz <= 0) return;                 // wave-uniform
  if (sz > TMAX * 64) sz = TMAX * 64;  // safety clamp (cannot trigger at 8 sigma)

  const uint32_t ku0 = KU.a, ku1 = KU.b, kv0 = KV.a, kv1 = KV.b;  // constexpr
  const uint32_t vt = vthresh[k];
  const float kf = (float)k;
  const uint32_t bbase = (uint32_t)(b << 16);

  // --- hoist ALL idx loads first: one vmcnt wait, hash loop is pure ALU -----
  int nv[TMAX];
#pragma unroll
  for (int t = 0; t < TMAX; ++t) {
    const int j = lane + (t << 6);
    nv[t] = (j < sz) ? idx_sorted[st + j] : 0;
  }

  // --- hash u,v per element; key bits + running per-lane min in registers ---
  uint32_t kb[TMAX];
  uint32_t curmin = 0xFFFFFFFFu;
  int cnt = 0;
#pragma unroll
  for (int t = 0; t < TMAX; ++t) {
    const int j = lane + (t << 6);
    uint32_t kbv = 0xFFFFFFFFu;        // sentinel > any valid key's bits
    if (j < sz) {
      const uint32_t f = bbase + (uint32_t)nv[t];   // flat index b*65536+n
      const uint32_t ubv = jax_bits(ku0, ku1, f);
      const uint32_t vbv = jax_bits(kv0, kv1, f);
      cnt += ((vbv >> 9) < vt) ? 1 : 0;             // integer-domain bernoulli
      kbv = __float_as_uint(key_from_ubits(ubv, kf));  // key>=0 -> bits monotone
    }
    kb[t] = kbv;
    curmin = (kbv < curmin) ? kbv : curmin;
  }
  int C = wave_sum_i(cnt);
  if (C < 1) C = 1;                    // jnp.maximum(counts, 1); C <= sz

  // --- C-th smallest keybits by iterative wave-min extraction (E[C]=1.6) ----
  uint32_t consumed = 0;
  uint32_t Tkey;
  for (int e = 0;; ++e) {
    const uint32_t wmn = wave_min_u(curmin);
    if (e == C - 1) { Tkey = wmn; break; }
    const unsigned long long bal = __ballot(curmin == wmn);
    const int src = (int)__ffsll((long long)bal) - 1;
    if (lane == src) {                 // consume exactly one instance of wmn
      int ct = -1;
#pragma unroll
      for (int t = 0; t < TMAX; ++t)
        if (ct < 0 && !((consumed >> t) & 1u) && kb[t] == wmn) ct = t;
      consumed |= (1u << ct);
      uint32_t nm = 0xFFFFFFFFu;
#pragma unroll
      for (int t = 0; t < TMAX; ++t) {
        const uint32_t v = ((consumed >> t) & 1u) ? 0xFFFFFFFFu : kb[t];
        nm = (v < nm) ? v : nm;
      }
      curmin = nm;
    }
  }

  // --- exact tie resolution on (key, original index): ONE packed reduction --
  int packed = 0;
#pragma unroll
  for (int t = 0; t < TMAX; ++t) {
    packed += (kb[t] < Tkey) ? (1 << 16) : 0;
    packed += (kb[t] == Tkey) ? 1 : 0;
  }
  const int sred = wave_sum_i(packed);
  const int nbelow = sred >> 16;
  const int tieCnt = sred & 0xFFFF;
  const int r = C - nbelow;            // 1 <= r <= tieCnt

  int cutN = 0x7FFFFFFF;               // r == tieCnt: select all tied
  if (r < tieCnt) {                    // rare: pick r smallest original indices
    uint32_t cons2 = 0;
    for (int e = 0; e < r; ++e) {
      int mnN = 0x7FFFFFFF, mnT = 0;
#pragma unroll
      for (int t = 0; t < TMAX; ++t) {
        if (kb[t] == Tkey && !((cons2 >> t) & 1u)) {
          if (nv[t] < mnN) { mnN = nv[t]; mnT = t; }
        }
      }
      const int w = wave_min_i(mnN);
      cutN = w;
      const unsigned long long bal = __ballot(mnN == w);
      const int src = (int)__ffsll((long long)bal) - 1;
      if (lane == src) cons2 |= (1u << mnT);
    }
  }

  // --- scatter-write selected elements (output pre-zeroed) ------------------
  const size_t rowoff = (size_t)b * NCOLS;
  const bool allTies = (r >= tieCnt);
#pragma unroll
  for (int t = 0; t < TMAX; ++t) {
    const uint32_t v = kb[t];
    bool sel = (v < Tkey);
    if (!sel && v == Tkey) sel = allTies ? true : (nv[t] <= cutN);
    if (sel) {
      const size_t off = rowoff + (uint32_t)nv[t];
      out[off] = x[off];
    }
  }
}

// ---- host-side launch ------------------------------------------------------
extern "C" void kernel_launch(void* const* d_in, const int* in_sizes, int n_in,
                              void* d_out, int out_size, void* d_ws, size_t ws_size,
                              hipStream_t stream) {
  const float* x = (const float*)d_in[0];
  const float* w = (const float*)d_in[1];
  const int* assign = (const int*)d_in[2];
  float* out = (float*)d_out;
  uint32_t* ws = (uint32_t*)d_ws;

  // workspace layout (uint32 units)
  uint32_t* vthresh   = ws;                 // [64]
  int*      sizes     = (int*)(ws + 64);    // [64]
  int*      starts    = (int*)(ws + 128);   // [64]
  int*      blockhist = (int*)(ws + 192);   // [128*64]
  int*      idxs      = (int*)(ws + 192 + NBLK * KCL);  // [65536]

  k_zerohist<<<ZBLK, 256, 0, stream>>>((float4*)out, assign, blockhist);
  k_prescatter<<<NBLK, 256, 0, stream>>>(assign, blockhist, sizes, starts, w,
                                         vthresh, idxs);
  k_select<<<(NROWS * KCL) / 4, 256, 0, stream>>>(x, idxs, sizes, starts,
                                                  vthresh, out);
  (void)n_in; (void)in_sizes; (void)ws_size;
}